// Round 9
// baseline (19272.409 us; speedup 1.0000x reference)
//
#include <hip/hip_runtime.h>
#include <math.h>

// ---------- types / helpers ----------
typedef __attribute__((ext_vector_type(8))) short bf16x8;   // 8 bf16 = 4 VGPR
typedef __attribute__((ext_vector_type(4))) int   i32x4;
typedef __attribute__((ext_vector_type(4))) float f32x4;    // MFMA acc
typedef __attribute__((ext_vector_type(4))) unsigned short u16x4;

__device__ __forceinline__ unsigned short f2bf(float x) {   // round-to-nearest-even
  unsigned int u = __builtin_bit_cast(unsigned int, x);
  return (unsigned short)((u + 0x7fffu + ((u >> 16) & 1u)) >> 16);
}
__device__ __forceinline__ float bf2f(unsigned short h) {
  unsigned int u = ((unsigned int)h) << 16;
  return __builtin_bit_cast(float, u);
}
// tanh via hw exp2: tanh(z) = 1 - 2/(e^{2z}+1)
__device__ __forceinline__ float fast_tanh(float z) {
  float e;
  asm("v_exp_f32 %0, %1" : "=v"(e) : "v"(z * 2.8853900817779268f));
  return 1.0f - 2.0f * __builtin_amdgcn_rcpf(e + 1.0f);
}

// ---------- K0: convert weights to bf16; seed hx pair-slices ----------
// hx layout: [pair 32][slice 2][batch-in-pair 2][1024] bf16 (256 KB total).
// regions (elem units, e = idx*4):
//   [0, 2097152)          w_i2h -> wx | wh
//   [2097152, 3145728)    w_h2o -> w2o
//   [3145728, 3211264)    h0 -> hx slice0, tag bits 00 (rounded insert)
//   [3211264, 3276800)    hx slice1 <- 0x0003 (invalid tag 0b11)
__global__ void convert_kernel(const float* __restrict__ w_i2h,
                               const float* __restrict__ w_h2o,
                               const float* __restrict__ h0,
                               unsigned short* __restrict__ wx,
                               unsigned short* __restrict__ wh,
                               unsigned short* __restrict__ w2o,
                               unsigned short* __restrict__ hx) {
  int idx = blockIdx.x * 256 + threadIdx.x;
  int e = idx * 4;
  if (e >= 3276800) return;
  if (e >= 3211264) {                      // hx slice1 invalid fill
    int i = e - 3211264;
    int b = i >> 10, j = i & 1023;
    int off = (b >> 1) * 4096 + 2048 + (b & 1) * 1024 + j;
    *(u16x4*)(hx + off) = (u16x4){3, 3, 3, 3};
    return;
  }
  if (e >= 3145728) {                      // h0 -> hx slice0 (tag 00)
    int i = e - 3145728;
    int b = i >> 10, j = i & 1023;
    float4 v = *(const float4*)(h0 + i);
    u16x4 o = {f2bf(v.x), f2bf(v.y), f2bf(v.z), f2bf(v.w)};
#pragma unroll
    for (int k = 0; k < 4; ++k)
      o[k] = (unsigned short)(((unsigned int)o[k] + 2u) & 0xFFFCu);
    int off = (b >> 1) * 4096 + (b & 1) * 1024 + j;
    *(u16x4*)(hx + off) = o;
    return;
  }
  const float* src;
  unsigned short* dst;
  if (e < 2097152) {                       // w_i2h
    int row = e >> 11, col = e & 2047;
    src = w_i2h + e;
    dst = (col < 1024) ? (wx + row * 1024 + col) : (wh + row * 1024 + (col - 1024));
  } else {                                 // w_h2o
    int i = e - 2097152; src = w_h2o + i; dst = w2o + i;
  }
  float4 v = *(const float4*)src;
  u16x4 o = {f2bf(v.x), f2bf(v.y), f2bf(v.z), f2bf(v.w)};
  *(u16x4*)dst = o;
}

// ---------- GEMM: C[M,N] = A[M,K] * B[N,K]^T + bias[N] ----------
// 128x128 tile, BK=64, 4 waves (2x2 of 64x64), 16x16x32 bf16 MFMA.
template <bool AF32, bool OUTBF16>
__global__ __launch_bounds__(256) void gemm_bt(const void* __restrict__ Ap,
                                               const unsigned short* __restrict__ B,
                                               const float* __restrict__ bias,
                                               void* __restrict__ Cp,
                                               int M, int N, int K) {
  __shared__ __attribute__((aligned(16))) unsigned short lA[128 * 64];
  __shared__ __attribute__((aligned(16))) unsigned short lB[128 * 64];
  const int tid = threadIdx.x;
  const int bx = blockIdx.x & 7;       // N/128 == 8
  const int by = blockIdx.x >> 3;
  const int lane = tid & 63, w = tid >> 6;
  const int g = lane >> 4, l15 = lane & 15;
  const int wm = w >> 1, wn = w & 1;

  f32x4 acc[4][4];
#pragma unroll
  for (int i = 0; i < 4; ++i)
#pragma unroll
    for (int j = 0; j < 4; ++j) acc[i][j] = (f32x4){0.f, 0.f, 0.f, 0.f};

  const int nK = K >> 6;
  for (int kt = 0; kt < nK; ++kt) {
    const int k0 = kt << 6;
#pragma unroll
    for (int i = 0; i < 4; ++i) {
      int cl = i * 256 + tid;
      int row = cl >> 3, cc = cl & 7;
      bf16x8 av;
      if (AF32) {
        const float* ap = (const float*)Ap + (size_t)(by * 128 + row) * K + k0 + cc * 8;
        float4 f0 = *(const float4*)ap;
        float4 f1 = *(const float4*)(ap + 4);
        av = (bf16x8){(short)f2bf(f0.x), (short)f2bf(f0.y), (short)f2bf(f0.z), (short)f2bf(f0.w),
                      (short)f2bf(f1.x), (short)f2bf(f1.y), (short)f2bf(f1.z), (short)f2bf(f1.w)};
      } else {
        const unsigned short* ap = (const unsigned short*)Ap + (size_t)(by * 128 + row) * K + k0 + cc * 8;
        av = *(const bf16x8*)ap;
      }
      *(bf16x8*)&lA[(row * 8 + (cc ^ (row & 7))) * 8] = av;
      const unsigned short* bp = B + (size_t)(bx * 128 + row) * K + k0 + cc * 8;
      bf16x8 bv = *(const bf16x8*)bp;
      *(bf16x8*)&lB[(row * 8 + (cc ^ (row & 7))) * 8] = bv;
    }
    __syncthreads();
#pragma unroll
    for (int kk = 0; kk < 2; ++kk) {
      bf16x8 av[4], bv[4];
#pragma unroll
      for (int mt = 0; mt < 4; ++mt) {
        int r = wm * 64 + mt * 16 + l15;
        av[mt] = *(const bf16x8*)&lA[(r * 8 + ((kk * 4 + g) ^ (r & 7))) * 8];
      }
#pragma unroll
      for (int nt = 0; nt < 4; ++nt) {
        int r = wn * 64 + nt * 16 + l15;
        bv[nt] = *(const bf16x8*)&lB[(r * 8 + ((kk * 4 + g) ^ (r & 7))) * 8];
      }
#pragma unroll
      for (int mt = 0; mt < 4; ++mt)
#pragma unroll
        for (int nt = 0; nt < 4; ++nt)
          acc[mt][nt] = __builtin_amdgcn_mfma_f32_16x16x32_bf16(av[mt], bv[nt], acc[mt][nt], 0, 0, 0);
    }
    __syncthreads();
  }
#pragma unroll
  for (int mt = 0; mt < 4; ++mt) {
    int grow = by * 128 + wm * 64 + mt * 16 + g * 4;
#pragma unroll
    for (int nt = 0; nt < 4; ++nt) {
      int col = bx * 128 + wn * 64 + nt * 16 + l15;
      float bs = bias[col];
#pragma unroll
      for (int r = 0; r < 4; ++r) {
        size_t off = (size_t)(grow + r) * N + col;
        float v = acc[mt][nt][r] + bs;
        if (OUTBF16) ((unsigned short*)Cp)[off] = f2bf(v);
        else ((float*)Cp)[off] = v;
      }
    }
  }
}

// ---------- K2: persistent scan, QUAD decomposition (group size = 4) ----------
// 128 blocks x 512 threads (8 waves, ~450 VGPR, 1 block/CU).
// Pair pid = blockIdx&31 owns batches {2pid, 2pid+1}; quarter q = blockIdx>>5
// owns j in [q*256, q*256+256). wh slice (256x1024 bf16 = 512 KB) register-
// resident all 512 steps. Exchange with the 3 sibling blocks via tagged
// sc0sc1 stores; the B-fragment load IS the poll. No intra-block barrier, no
// LDS. All lanes load duplicate batch rows (l15&1); D cols 0,1 valid; lanes
// l15<2 store. Wave-collective retry (R4-proven) + bounded escape.
#define SCAN_BLOCKS 128
__global__ __launch_bounds__(512, 2) void rnn_scan(const unsigned short* __restrict__ xproj,
                                                   const unsigned short* __restrict__ wh,
                                                   unsigned short* __restrict__ h_all,
                                                   unsigned short* __restrict__ hx) {
  const int tid = threadIdx.x;            // 0..511
  const int b = blockIdx.x;
  const int pid = b & 31, q = b >> 5;
  const int w = tid >> 6, lane = tid & 63;
  const int g = lane >> 4, l15 = lane & 15;
  const int bi = l15 & 1;                 // duplicated batch parity
  const int b0 = pid * 2;
  const int jw = q * 256 + w * 32;        // wave's 2 j-tiles: jw, jw+16

  // wh A-fragments, register-resident for all 512 steps (256 VGPR):
  bf16x8 wa[2][32];
#pragma unroll
  for (int jt2 = 0; jt2 < 2; ++jt2)
#pragma unroll
    for (int kk = 0; kk < 32; ++kk)
      wa[jt2][kk] = *(const bf16x8*)(wh + (size_t)(jw + jt2 * 16 + l15) * 1024 + kk * 32 + g * 8);

  unsigned short* hxp = hx + pid * 4096;  // pair base: [slice 2][batch 2][1024]
  const int cofs = bi * 1024 + g * 8;     // chunk-load offset (+ sl*2048 + kk*32)
  const int j00 = jw + g * 4;             // jt2=0 producer j base (jt2=1: +16)

  uint2 xpc0 = *(const uint2*)(xproj + (size_t)(b0 + bi) * 1024 + j00);
  uint2 xpc1 = *(const uint2*)(xproj + (size_t)(b0 + bi) * 1024 + j00 + 16);

  for (int t = 0; t < 512; ++t) {
    const int sl = t & 1;
    const unsigned short* src = hxp + sl * 2048;
    unsigned short*       dst = hxp + (sl ^ 1) * 2048;
    const unsigned int pat2 = (unsigned int)((t >> 1) & 1) * 0x00010001u;

    // --- poll = B-fragment load; wave-collective retry until all fresh ---
    i32x4 c[32];
    bool allok;
    int rounds = 0;
    do {
#pragma unroll
      for (int kk = 0; kk < 32; ++kk) {
        const unsigned short* p = src + cofs + kk * 32;
        asm volatile("global_load_dwordx4 %0, %1, off sc0 sc1"
                     : "=v"(c[kk]) : "v"(p) : "memory");
      }
      asm volatile("s_waitcnt vmcnt(0)" ::: "memory");
      __builtin_amdgcn_sched_barrier(0);
      unsigned int bad = 0;
#pragma unroll
      for (int kk = 0; kk < 32; ++kk) {
        bad |= ((unsigned int)c[kk][0] ^ pat2) & 0x00030003u;
        bad |= ((unsigned int)c[kk][1] ^ pat2) & 0x00030003u;
        bad |= ((unsigned int)c[kk][2] ^ pat2) & 0x00030003u;
        bad |= ((unsigned int)c[kk][3] ^ pat2) & 0x00030003u;
      }
      allok = (bad == 0);
      if (++rounds > (1 << 22)) break;    // bounded escape (protocol-sound => unreachable)
    } while (__any(!allok));
    __builtin_amdgcn_sched_barrier(0);

    // prefetch next step's xp (plain cached; overlaps MFMA)
    int tn = (t < 511) ? (t + 1) : 511;
    uint2 xpn0 = *(const uint2*)(xproj + (size_t)tn * 65536 + (size_t)(b0 + bi) * 1024 + j00);
    uint2 xpn1 = *(const uint2*)(xproj + (size_t)tn * 65536 + (size_t)(b0 + bi) * 1024 + j00 + 16);

    // --- MFMA: D[j = jw+jt2*16+g*4+r][col = l15] (cols 0,1 valid) ---
    f32x4 acc[2][4];
#pragma unroll
    for (int jt2 = 0; jt2 < 2; ++jt2)
#pragma unroll
      for (int i = 0; i < 4; ++i) acc[jt2][i] = (f32x4){0.f, 0.f, 0.f, 0.f};
#pragma unroll
    for (int kk = 0; kk < 32; ++kk) {
      bf16x8 hb = __builtin_bit_cast(bf16x8, c[kk]);
      acc[0][kk & 3] = __builtin_amdgcn_mfma_f32_16x16x32_bf16(wa[0][kk], hb, acc[0][kk & 3], 0, 0, 0);
      acc[1][kk & 3] = __builtin_amdgcn_mfma_f32_16x16x32_bf16(wa[1][kk], hb, acc[1][kk & 3], 0, 0, 0);
    }

    // --- epilogue: only lanes l15<2 are producers ---
    const unsigned int tagn = (unsigned int)(((t + 1) >> 1) & 1);
    if (l15 < 2) {
#pragma unroll
      for (int jt2 = 0; jt2 < 2; ++jt2) {
        f32x4 s = (acc[jt2][0] + acc[jt2][1]) + (acc[jt2][2] + acc[jt2][3]);
        uint2 xpc = jt2 ? xpc1 : xpc0;
        float z0 = s[0] + bf2f((unsigned short)(xpc.x & 0xFFFF));
        float z1 = s[1] + bf2f((unsigned short)(xpc.x >> 16));
        float z2 = s[2] + bf2f((unsigned short)(xpc.y & 0xFFFF));
        float z3 = s[3] + bf2f((unsigned short)(xpc.y >> 16));
        unsigned int h0v = (((unsigned int)f2bf(fast_tanh(z0)) + 2u) & 0xFFFCu) | tagn;
        unsigned int h1v = (((unsigned int)f2bf(fast_tanh(z1)) + 2u) & 0xFFFCu) | tagn;
        unsigned int h2v = (((unsigned int)f2bf(fast_tanh(z2)) + 2u) & 0xFFFCu) | tagn;
        unsigned int h3v = (((unsigned int)f2bf(fast_tanh(z3)) + 2u) & 0xFFFCu) | tagn;
        uint2 dvec = {h0v | (h1v << 16), h2v | (h3v << 16)};
        int j0 = j00 + jt2 * 16;
        // tagged exchange store (fire-and-forget, no drain)
        unsigned short* pd = dst + l15 * 1024 + j0;
        asm volatile("global_store_dwordx2 %0, %1, off sc0 sc1"
                     :: "v"(pd), "v"(dvec) : "memory");
        // dense h for the output GEMM (plain cached store)
        *(uint2*)(h_all + (size_t)t * 65536 + (size_t)(b0 + l15) * 1024 + j0) = dvec;
      }
    }
    xpc0 = xpn0;
    xpc1 = xpn1;
  }
}

// ---------- launch ----------
extern "C" void kernel_launch(void* const* d_in, const int* in_sizes, int n_in,
                              void* d_out, int out_size, void* d_ws, size_t ws_size,
                              hipStream_t stream) {
  const float* x     = (const float*)d_in[0];   // (512,64,1024)
  const float* h0    = (const float*)d_in[1];   // (64,1024)
  const float* w_i2h = (const float*)d_in[2];   // (1024,2048)
  const float* b_i2h = (const float*)d_in[3];   // (1024)
  const float* w_h2o = (const float*)d_in[4];   // (1024,1024)
  const float* b_h2o = (const float*)d_in[5];   // (1024)

  // workspace: h_all (67,108,864) | hx (262,144) | wx 2MB | wh 2MB | w2o 2MB
  char* ws = (char*)d_ws;
  unsigned short* h_all = (unsigned short*)ws;
  unsigned short* hx    = (unsigned short*)(ws + 67108864);
  unsigned short* wx    = (unsigned short*)(ws + 67108864 + 262144);
  unsigned short* wh    = wx + 1024 * 1024;
  unsigned short* w2o   = wh + 1024 * 1024;
  // d_out (128MB fp32 y): first 64MB doubles as bf16 xproj (dead before gemm2).
  unsigned short* xproj = (unsigned short*)d_out;

  convert_kernel<<<3200, 256, 0, stream>>>(w_i2h, w_h2o, h0, wx, wh, w2o, hx);

  // xproj = x @ wx^T + b_i2h   (M=32768, N=1024, K=1024)
  gemm_bt<true, true><<<2048, 256, 0, stream>>>((const void*)x, wx, b_i2h,
                                                (void*)xproj, 32768, 1024, 1024);

  // persistent 512-step recurrence (quad-group tagged exchange)
  rnn_scan<<<SCAN_BLOCKS, 512, 0, stream>>>(xproj, wh, h_all, hx);

  // Y = h_all (= h[1..512]) @ w_h2o^T + b_h2o  -> d_out (fp32)
  gemm_bt<false, false><<<2048, 256, 0, stream>>>((const void*)h_all, w2o, b_h2o,
                                                  d_out, 32768, 1024, 1024);
}

// Round 11
// 1673.821 us; speedup vs baseline: 11.5140x; 11.5140x over previous
//
#include <hip/hip_runtime.h>
#include <math.h>

// ---------- types / helpers ----------
typedef __attribute__((ext_vector_type(8))) short bf16x8;   // 8 bf16 = 4 VGPR
typedef __attribute__((ext_vector_type(4))) int   i32x4;
typedef __attribute__((ext_vector_type(4))) float f32x4;    // MFMA acc
typedef __attribute__((ext_vector_type(4))) unsigned short u16x4;

__device__ __forceinline__ unsigned short f2bf(float x) {   // round-to-nearest-even
  unsigned int u = __builtin_bit_cast(unsigned int, x);
  return (unsigned short)((u + 0x7fffu + ((u >> 16) & 1u)) >> 16);
}
__device__ __forceinline__ float bf2f(unsigned short h) {
  unsigned int u = ((unsigned int)h) << 16;
  return __builtin_bit_cast(float, u);
}
// tanh via hw exp2: tanh(z) = 1 - 2/(e^{2z}+1)
__device__ __forceinline__ float fast_tanh(float z) {
  float e;
  asm("v_exp_f32 %0, %1" : "=v"(e) : "v"(z * 2.8853900817779268f));
  return 1.0f - 2.0f * __builtin_amdgcn_rcpf(e + 1.0f);
}

// ---------- K0: convert weights + h0 to bf16; zero barrier flags ----------
__global__ void convert_kernel(const float* __restrict__ w_i2h,
                               const float* __restrict__ w_h2o,
                               const float* __restrict__ h0,
                               unsigned short* __restrict__ wx,
                               unsigned short* __restrict__ wh,
                               unsigned short* __restrict__ w2o,
                               unsigned short* __restrict__ hx,
                               int* __restrict__ flags) {
  int idx = blockIdx.x * 256 + threadIdx.x;
  if (idx < 256) flags[idx] = 0;           // barrier flags for rnn_scan
  int e = idx * 4;
  const float* src;
  unsigned short* dst;
  if (e < 2097152) {                       // w_i2h
    int row = e >> 11, col = e & 2047;
    src = w_i2h + e;
    dst = (col < 1024) ? (wx + row * 1024 + col) : (wh + row * 1024 + (col - 1024));
  } else if (e < 3145728) {                // w_h2o
    int i = e - 2097152; src = w_h2o + i; dst = w2o + i;
  } else {                                 // h0 -> hx slice 0
    int i = e - 3145728; src = h0 + i; dst = hx + i;
  }
  float4 v = *(const float4*)src;
  u16x4 o = {f2bf(v.x), f2bf(v.y), f2bf(v.z), f2bf(v.w)};
  *(u16x4*)dst = o;
}

// ---------- GEMM: C[M,N] = A[M,K] * B[N,K]^T + bias[N] ----------
// 128x128 tile, BK=64, 4 waves (2x2 of 64x64), 16x16x32 bf16 MFMA.
template <bool AF32, bool OUTBF16>
__global__ __launch_bounds__(256) void gemm_bt(const void* __restrict__ Ap,
                                               const unsigned short* __restrict__ B,
                                               const float* __restrict__ bias,
                                               void* __restrict__ Cp,
                                               int M, int N, int K) {
  __shared__ __attribute__((aligned(16))) unsigned short lA[128 * 64];
  __shared__ __attribute__((aligned(16))) unsigned short lB[128 * 64];
  const int tid = threadIdx.x;
  const int bx = blockIdx.x & 7;       // N/128 == 8
  const int by = blockIdx.x >> 3;
  const int lane = tid & 63, w = tid >> 6;
  const int g = lane >> 4, l15 = lane & 15;
  const int wm = w >> 1, wn = w & 1;

  f32x4 acc[4][4];
#pragma unroll
  for (int i = 0; i < 4; ++i)
#pragma unroll
    for (int j = 0; j < 4; ++j) acc[i][j] = (f32x4){0.f, 0.f, 0.f, 0.f};

  const int nK = K >> 6;
  for (int kt = 0; kt < nK; ++kt) {
    const int k0 = kt << 6;
#pragma unroll
    for (int i = 0; i < 4; ++i) {
      int cl = i * 256 + tid;
      int row = cl >> 3, cc = cl & 7;
      bf16x8 av;
      if (AF32) {
        const float* ap = (const float*)Ap + (size_t)(by * 128 + row) * K + k0 + cc * 8;
        float4 f0 = *(const float4*)ap;
        float4 f1 = *(const float4*)(ap + 4);
        av = (bf16x8){(short)f2bf(f0.x), (short)f2bf(f0.y), (short)f2bf(f0.z), (short)f2bf(f0.w),
                      (short)f2bf(f1.x), (short)f2bf(f1.y), (short)f2bf(f1.z), (short)f2bf(f1.w)};
      } else {
        const unsigned short* ap = (const unsigned short*)Ap + (size_t)(by * 128 + row) * K + k0 + cc * 8;
        av = *(const bf16x8*)ap;
      }
      *(bf16x8*)&lA[(row * 8 + (cc ^ (row & 7))) * 8] = av;
      const unsigned short* bp = B + (size_t)(bx * 128 + row) * K + k0 + cc * 8;
      bf16x8 bv = *(const bf16x8*)bp;
      *(bf16x8*)&lB[(row * 8 + (cc ^ (row & 7))) * 8] = bv;
    }
    __syncthreads();
#pragma unroll
    for (int kk = 0; kk < 2; ++kk) {
      bf16x8 av[4], bv[4];
#pragma unroll
      for (int mt = 0; mt < 4; ++mt) {
        int r = wm * 64 + mt * 16 + l15;
        av[mt] = *(const bf16x8*)&lA[(r * 8 + ((kk * 4 + g) ^ (r & 7))) * 8];
      }
#pragma unroll
      for (int nt = 0; nt < 4; ++nt) {
        int r = wn * 64 + nt * 16 + l15;
        bv[nt] = *(const bf16x8*)&lB[(r * 8 + ((kk * 4 + g) ^ (r & 7))) * 8];
      }
#pragma unroll
      for (int mt = 0; mt < 4; ++mt)
#pragma unroll
        for (int nt = 0; nt < 4; ++nt)
          acc[mt][nt] = __builtin_amdgcn_mfma_f32_16x16x32_bf16(av[mt], bv[nt], acc[mt][nt], 0, 0, 0);
    }
    __syncthreads();
  }
#pragma unroll
  for (int mt = 0; mt < 4; ++mt) {
    int grow = by * 128 + wm * 64 + mt * 16 + g * 4;
#pragma unroll
    for (int nt = 0; nt < 4; ++nt) {
      int col = bx * 128 + wn * 64 + nt * 16 + l15;
      float bs = bias[col];
#pragma unroll
      for (int r = 0; r < 4; ++r) {
        size_t off = (size_t)(grow + r) * N + col;
        float v = acc[mt][nt][r] + bs;
        if (OUTBF16) ((unsigned short*)Cp)[off] = f2bf(v);
        else ((float*)Cp)[off] = v;
      }
    }
  }
}

// ---------- K2: persistent scan + FUSED output GEMM (shifted fusion) ----------
// R3 structure: 256 blocks x 1 wave; block (jt,bt) owns 16 j/o-cols x 16
// batches; per-bt-group flag barrier; sc0sc1 exchange via L3; hx = 4-slice
// ring (flag ordering bounds lag, so slice t&3 is safe).
// Fusion (off-by-one CORRECTED): reference y[t] = h[t+1] @ w2o^T + b. At
// iteration t we load ha = h[t], so we emit y[t-1] from ha — in the latency
// shadow after publishing our flag. Loop runs t = 0..512 inclusive; the last
// iteration only loads h[512] and emits y[511].
#define SCAN_BLOCKS 256
__global__ __launch_bounds__(64, 1) void rnn_scan(const unsigned short* __restrict__ xproj,
                                                  const unsigned short* __restrict__ wh,
                                                  const unsigned short* __restrict__ w2o,
                                                  const float* __restrict__ b_h2o,
                                                  float* __restrict__ y,
                                                  unsigned short* __restrict__ hx,
                                                  int* __restrict__ flags) {
  const int tid = threadIdx.x;          // 0..63
  const int b = blockIdx.x;
  const int jt = b >> 2, bt = b & 3;
  const int g = tid >> 4, l15 = tid & 15;
  const int j0 = jt * 16, b0 = bt * 16;

  // resident B-fragments: wh rows (recurrence) and w2o rows (output GEMM)
  bf16x8 wb[32], wo[32];
#pragma unroll
  for (int kk = 0; kk < 32; ++kk) {
    wb[kk] = *(const bf16x8*)(wh  + (size_t)(j0 + l15) * 1024 + kk * 32 + g * 8);
    wo[kk] = *(const bf16x8*)(w2o + (size_t)(j0 + l15) * 1024 + kk * 32 + g * 8);
  }
  const float bias_o = b_h2o[j0 + l15];

  const int* fl = flags + bt * 64 + tid;   // lane tid polls producer jt'=tid of my bt group
  int* myflag = flags + bt * 64 + jt;

  for (int t = 0; t <= 512; ++t) {
    const unsigned short* hsrc = hx + (size_t)(t & 3) * 65536 + (size_t)b0 * 1024;

    // prefetch xp for the recurrence (skip on the drain iteration)
    float xpv[4];
    if (t < 512) {
      const unsigned short* xp = xproj + (size_t)t * 65536;
#pragma unroll
      for (int r = 0; r < 4; ++r)
        xpv[r] = bf2f(xp[(size_t)(b0 + g * 4 + r) * 1024 + j0 + l15]);
    }

    // barrier: wait for all 64 producers of my bt group (one coherent load/lane)
    int v;
    do {
      asm volatile("global_load_dword %0, %1, off sc0 sc1\n\ts_waitcnt vmcnt(0)"
                   : "=v"(v) : "v"(fl) : "memory");
    } while (__any(v < t));

    // coherent h[t] loads: bypass L1/L2, read L3 (cross-XCD coherence point)
    i32x4 ha[32];
#pragma unroll
    for (int kk = 0; kk < 32; ++kk) {
      const unsigned short* p = hsrc + (size_t)l15 * 1024 + kk * 32 + g * 8;
      asm volatile("global_load_dwordx4 %0, %1, off sc0 sc1"
                   : "=v"(ha[kk]) : "v"(p) : "memory");
    }

    if (t < 512) {
      unsigned short* hdst = hx + (size_t)((t + 1) & 3) * 65536;
      f32x4 acc[4];
#pragma unroll
      for (int i = 0; i < 4; ++i) acc[i] = (f32x4){0.f, 0.f, 0.f, 0.f};

      // pipelined consume: counted vmcnt + sched_barrier (rule 18)
#define MFMA_GROUP(base, n)                                                     \
      asm volatile("s_waitcnt vmcnt(" #n ")" ::: "memory");                     \
      __builtin_amdgcn_sched_barrier(0);                                        \
      _Pragma("unroll")                                                         \
      for (int kk = base; kk < base + 8; ++kk)                                  \
        acc[kk & 3] = __builtin_amdgcn_mfma_f32_16x16x32_bf16(                  \
            __builtin_bit_cast(bf16x8, ha[kk]), wb[kk], acc[kk & 3], 0, 0, 0);

      MFMA_GROUP(0, 24)
      MFMA_GROUP(8, 16)
      MFMA_GROUP(16, 8)
      MFMA_GROUP(24, 0)
#undef MFMA_GROUP

      f32x4 s = (acc[0] + acc[1]) + (acc[2] + acc[3]);

      // h_next = tanh(s + xp), coherent 2B stores (write-through to L3)
#pragma unroll
      for (int r = 0; r < 4; ++r) {
        float z = s[r] + xpv[r];
        unsigned int hv = f2bf(fast_tanh(z));
        unsigned short* p = hdst + (size_t)(b0 + g * 4 + r) * 1024 + j0 + l15;
        asm volatile("global_store_short %0, %1, off sc0 sc1"
                     :: "v"(p), "v"(hv) : "memory");
      }
      // order h stores before flag publish; publish ASAP (critical path)
      asm volatile("s_waitcnt vmcnt(0)" ::: "memory");
      if (tid == 0) {
        int tv = t + 1;
        asm volatile("global_store_dword %0, %1, off sc0 sc1"
                     :: "v"(myflag), "v"(tv) : "memory");
      }
    } else {
      // drain iteration: just make sure h[512] fragments have landed
      asm volatile("s_waitcnt vmcnt(0)" ::: "memory");
      __builtin_amdgcn_sched_barrier(0);
    }

    // ---- fused y-tile (latency shadow): y[t-1] = h[t] @ w2o^T + b ----
    if (t > 0) {
      f32x4 ay[4];
#pragma unroll
      for (int i = 0; i < 4; ++i) ay[i] = (f32x4){0.f, 0.f, 0.f, 0.f};
#pragma unroll
      for (int kk = 0; kk < 32; ++kk)
        ay[kk & 3] = __builtin_amdgcn_mfma_f32_16x16x32_bf16(
            __builtin_bit_cast(bf16x8, ha[kk]), wo[kk], ay[kk & 3], 0, 0, 0);
      f32x4 sy = (ay[0] + ay[1]) + (ay[2] + ay[3]);
#pragma unroll
      for (int r = 0; r < 4; ++r)
        y[(size_t)(t - 1) * 65536 + (size_t)(b0 + g * 4 + r) * 1024 + j0 + l15] = sy[r] + bias_o;
    }
  }
}

// ---------- launch ----------
extern "C" void kernel_launch(void* const* d_in, const int* in_sizes, int n_in,
                              void* d_out, int out_size, void* d_ws, size_t ws_size,
                              hipStream_t stream) {
  const float* x     = (const float*)d_in[0];   // (512,64,1024)
  const float* h0    = (const float*)d_in[1];   // (64,1024)
  const float* w_i2h = (const float*)d_in[2];   // (1024,2048)
  const float* b_i2h = (const float*)d_in[3];   // (1024)
  const float* w_h2o = (const float*)d_in[4];   // (1024,1024)
  const float* b_h2o = (const float*)d_in[5];   // (1024)

  // workspace: xproj bf16 (67,108,864) | hx 4 slices (524,288) | flags (4,096)
  //            | wx 2MB | wh 2MB | w2o 2MB   (~73.9 MB)
  char* ws = (char*)d_ws;
  unsigned short* xproj = (unsigned short*)ws;
  unsigned short* hx    = (unsigned short*)(ws + 67108864);
  int*            flags = (int*)(ws + 67108864 + 524288);
  unsigned short* wx    = (unsigned short*)(ws + 67108864 + 524288 + 4096);
  unsigned short* wh    = wx + 1024 * 1024;
  unsigned short* w2o   = wh + 1024 * 1024;
  float* y = (float*)d_out;                      // (512,64,1024) fp32

  convert_kernel<<<3136, 256, 0, stream>>>(w_i2h, w_h2o, h0, wx, wh, w2o, hx, flags);

  // xproj = x @ wx^T + b_i2h   (M=32768, N=1024, K=1024) -> ws
  gemm_bt<true, true><<<2048, 256, 0, stream>>>((const void*)x, wx, b_i2h,
                                                (void*)xproj, 32768, 1024, 1024);

  // persistent 512-step recurrence with fused (shifted) output GEMM -> d_out
  rnn_scan<<<SCAN_BLOCKS, 64, 0, stream>>>(xproj, wh, w2o, b_h2o, y, hx, flags);
}

// Round 12
// 1537.457 us; speedup vs baseline: 12.5352x; 1.0887x over previous
//
#include <hip/hip_runtime.h>
#include <math.h>

// ---------- types / helpers ----------
typedef __attribute__((ext_vector_type(8))) short bf16x8;   // 8 bf16 = 4 VGPR
typedef __attribute__((ext_vector_type(4))) int   i32x4;
typedef __attribute__((ext_vector_type(4))) float f32x4;    // MFMA acc
typedef __attribute__((ext_vector_type(4))) unsigned short u16x4;

__device__ __forceinline__ unsigned short f2bf(float x) {   // round-to-nearest-even
  unsigned int u = __builtin_bit_cast(unsigned int, x);
  return (unsigned short)((u + 0x7fffu + ((u >> 16) & 1u)) >> 16);
}
__device__ __forceinline__ float bf2f(unsigned short h) {
  unsigned int u = ((unsigned int)h) << 16;
  return __builtin_bit_cast(float, u);
}
// tanh via hw exp2: tanh(z) = 1 - 2/(e^{2z}+1)
__device__ __forceinline__ float fast_tanh(float z) {
  float e;
  asm("v_exp_f32 %0, %1" : "=v"(e) : "v"(z * 2.8853900817779268f));
  return 1.0f - 2.0f * __builtin_amdgcn_rcpf(e + 1.0f);
}

// ---------- K0: convert weights + h0 to bf16; zero barrier flags ----------
__global__ void convert_kernel(const float* __restrict__ w_i2h,
                               const float* __restrict__ w_h2o,
                               const float* __restrict__ h0,
                               unsigned short* __restrict__ wx,
                               unsigned short* __restrict__ wh,
                               unsigned short* __restrict__ w2o,
                               unsigned short* __restrict__ hx,
                               int* __restrict__ flags) {
  int idx = blockIdx.x * 256 + threadIdx.x;
  if (idx < 4096) flags[idx] = 0;          // padded flags (256 x 64B lines)
  int e = idx * 4;
  const float* src;
  unsigned short* dst;
  if (e < 2097152) {                       // w_i2h
    int row = e >> 11, col = e & 2047;
    src = w_i2h + e;
    dst = (col < 1024) ? (wx + row * 1024 + col) : (wh + row * 1024 + (col - 1024));
  } else if (e < 3145728) {                // w_h2o
    int i = e - 2097152; src = w_h2o + i; dst = w2o + i;
  } else {                                 // h0 -> hx slice 0
    int i = e - 3145728; src = h0 + i; dst = hx + i;
  }
  float4 v = *(const float4*)src;
  u16x4 o = {f2bf(v.x), f2bf(v.y), f2bf(v.z), f2bf(v.w)};
  *(u16x4*)dst = o;
}

// ---------- GEMM: C[M,N] = A[M,K] * B[N,K]^T + bias[N] ----------
// 128x128 tile, BK=64, 4 waves (2x2 of 64x64), 16x16x32 bf16 MFMA.
template <bool AF32, bool OUTBF16>
__global__ __launch_bounds__(256) void gemm_bt(const void* __restrict__ Ap,
                                               const unsigned short* __restrict__ B,
                                               const float* __restrict__ bias,
                                               void* __restrict__ Cp,
                                               int M, int N, int K) {
  __shared__ __attribute__((aligned(16))) unsigned short lA[128 * 64];
  __shared__ __attribute__((aligned(16))) unsigned short lB[128 * 64];
  const int tid = threadIdx.x;
  const int bx = blockIdx.x & 7;       // N/128 == 8
  const int by = blockIdx.x >> 3;
  const int lane = tid & 63, w = tid >> 6;
  const int g = lane >> 4, l15 = lane & 15;
  const int wm = w >> 1, wn = w & 1;

  f32x4 acc[4][4];
#pragma unroll
  for (int i = 0; i < 4; ++i)
#pragma unroll
    for (int j = 0; j < 4; ++j) acc[i][j] = (f32x4){0.f, 0.f, 0.f, 0.f};

  const int nK = K >> 6;
  for (int kt = 0; kt < nK; ++kt) {
    const int k0 = kt << 6;
#pragma unroll
    for (int i = 0; i < 4; ++i) {
      int cl = i * 256 + tid;
      int row = cl >> 3, cc = cl & 7;
      bf16x8 av;
      if (AF32) {
        const float* ap = (const float*)Ap + (size_t)(by * 128 + row) * K + k0 + cc * 8;
        float4 f0 = *(const float4*)ap;
        float4 f1 = *(const float4*)(ap + 4);
        av = (bf16x8){(short)f2bf(f0.x), (short)f2bf(f0.y), (short)f2bf(f0.z), (short)f2bf(f0.w),
                      (short)f2bf(f1.x), (short)f2bf(f1.y), (short)f2bf(f1.z), (short)f2bf(f1.w)};
      } else {
        const unsigned short* ap = (const unsigned short*)Ap + (size_t)(by * 128 + row) * K + k0 + cc * 8;
        av = *(const bf16x8*)ap;
      }
      *(bf16x8*)&lA[(row * 8 + (cc ^ (row & 7))) * 8] = av;
      const unsigned short* bp = B + (size_t)(bx * 128 + row) * K + k0 + cc * 8;
      bf16x8 bv = *(const bf16x8*)bp;
      *(bf16x8*)&lB[(row * 8 + (cc ^ (row & 7))) * 8] = bv;
    }
    __syncthreads();
#pragma unroll
    for (int kk = 0; kk < 2; ++kk) {
      bf16x8 av[4], bv[4];
#pragma unroll
      for (int mt = 0; mt < 4; ++mt) {
        int r = wm * 64 + mt * 16 + l15;
        av[mt] = *(const bf16x8*)&lA[(r * 8 + ((kk * 4 + g) ^ (r & 7))) * 8];
      }
#pragma unroll
      for (int nt = 0; nt < 4; ++nt) {
        int r = wn * 64 + nt * 16 + l15;
        bv[nt] = *(const bf16x8*)&lB[(r * 8 + ((kk * 4 + g) ^ (r & 7))) * 8];
      }
#pragma unroll
      for (int mt = 0; mt < 4; ++mt)
#pragma unroll
        for (int nt = 0; nt < 4; ++nt)
          acc[mt][nt] = __builtin_amdgcn_mfma_f32_16x16x32_bf16(av[mt], bv[nt], acc[mt][nt], 0, 0, 0);
    }
    __syncthreads();
  }
#pragma unroll
  for (int mt = 0; mt < 4; ++mt) {
    int grow = by * 128 + wm * 64 + mt * 16 + g * 4;
#pragma unroll
    for (int nt = 0; nt < 4; ++nt) {
      int col = bx * 128 + wn * 64 + nt * 16 + l15;
      float bs = bias[col];
#pragma unroll
      for (int r = 0; r < 4; ++r) {
        size_t off = (size_t)(grow + r) * N + col;
        float v = acc[mt][nt][r] + bs;
        if (OUTBF16) ((unsigned short*)Cp)[off] = f2bf(v);
        else ((float*)Cp)[off] = v;
      }
    }
  }
}

// ---------- K2: persistent scan + fused y-GEMM, operand-swapped ----------
// R11 structure (256 blocks x 1 wave; block (jt,bt): 16 j/o-cols x 16 batches;
// per-bt-group flag barrier; sc0sc1 L3 exchange; 4-slice hx ring; y[t-1]
// emitted from ha=h[t] in the poll shadow). Changes vs R11:
//  * MFMA operand swap: D = mfma(wb, ha) -> lane holds D[j0+g*4+r][b0+l15],
//    i.e. 4 j-CONSECUTIVE outputs for one batch. Fragment loads unchanged
//    (A-row and B-col share the lane mapping). Critical-path h-store becomes
//    ONE dwordx2/lane (was 4 strided 2B stores), xp load one dwordx2,
//    y store one dwordx4.
//  * Flags padded to one 64B line each (poll contention spread over 256 lines).
#define SCAN_BLOCKS 256
__global__ __launch_bounds__(64, 1) void rnn_scan(const unsigned short* __restrict__ xproj,
                                                  const unsigned short* __restrict__ wh,
                                                  const unsigned short* __restrict__ w2o,
                                                  const float* __restrict__ b_h2o,
                                                  float* __restrict__ y,
                                                  unsigned short* __restrict__ hx,
                                                  int* __restrict__ flags) {
  const int tid = threadIdx.x;          // 0..63
  const int b = blockIdx.x;
  const int jt = b >> 2, bt = b & 3;
  const int g = tid >> 4, l15 = tid & 15;
  const int j0 = jt * 16, b0 = bt * 16;

  // resident fragments: wh / w2o rows j0..j0+15 (lane l15 = row, g = k-slice)
  bf16x8 wb[32], wo[32];
#pragma unroll
  for (int kk = 0; kk < 32; ++kk) {
    wb[kk] = *(const bf16x8*)(wh  + (size_t)(j0 + l15) * 1024 + kk * 32 + g * 8);
    wo[kk] = *(const bf16x8*)(w2o + (size_t)(j0 + l15) * 1024 + kk * 32 + g * 8);
  }
  // after swap each lane outputs j = j0+g*4 .. +3 -> float4 bias
  const float4 bias_o = *(const float4*)(b_h2o + j0 + g * 4);

  const int* fl = flags + (bt * 64 + tid) * 16;   // 64B-padded flag lines
  int* myflag = flags + (bt * 64 + jt) * 16;

  // per-lane element offset for h-store / xp / y (batch b0+l15, j j0+g*4)
  const int pofs = (b0 + l15) * 1024 + j0 + g * 4;

  for (int t = 0; t <= 512; ++t) {
    const unsigned short* hsrc = hx + (size_t)(t & 3) * 65536 + (size_t)b0 * 1024;

    // prefetch xp for the recurrence (skip on the drain iteration)
    uint2 xpc;
    if (t < 512)
      xpc = *(const uint2*)(xproj + (size_t)t * 65536 + pofs);

    // barrier: wait for all 64 producers of my bt group (one coherent load/lane)
    int v;
    do {
      asm volatile("global_load_dword %0, %1, off sc0 sc1\n\ts_waitcnt vmcnt(0)"
                   : "=v"(v) : "v"(fl) : "memory");
    } while (__any(v < t));

    // coherent h[t] loads: B-fragments (lane l15 = batch col, g = k-slice)
    i32x4 ha[32];
#pragma unroll
    for (int kk = 0; kk < 32; ++kk) {
      const unsigned short* p = hsrc + (size_t)l15 * 1024 + kk * 32 + g * 8;
      asm volatile("global_load_dwordx4 %0, %1, off sc0 sc1"
                   : "=v"(ha[kk]) : "v"(p) : "memory");
    }

    if (t < 512) {
      unsigned short* hdst = hx + (size_t)((t + 1) & 3) * 65536;
      f32x4 acc[4];
#pragma unroll
      for (int i = 0; i < 4; ++i) acc[i] = (f32x4){0.f, 0.f, 0.f, 0.f};

      // pipelined consume: counted vmcnt + sched_barrier (rule 18)
      // D[r=j][c=batch] = sum_k wh[j0+r][k] * h[b0+c][k]
#define MFMA_GROUP(base, n)                                                     \
      asm volatile("s_waitcnt vmcnt(" #n ")" ::: "memory");                     \
      __builtin_amdgcn_sched_barrier(0);                                        \
      _Pragma("unroll")                                                         \
      for (int kk = base; kk < base + 8; ++kk)                                  \
        acc[kk & 3] = __builtin_amdgcn_mfma_f32_16x16x32_bf16(                  \
            wb[kk], __builtin_bit_cast(bf16x8, ha[kk]), acc[kk & 3], 0, 0, 0);

      MFMA_GROUP(0, 24)
      MFMA_GROUP(8, 16)
      MFMA_GROUP(16, 8)
      MFMA_GROUP(24, 0)
#undef MFMA_GROUP

      f32x4 s = (acc[0] + acc[1]) + (acc[2] + acc[3]);

      // h_next[b0+l15][j0+g*4 .. +3] = tanh(s + xp): ONE dwordx2 store
      {
        float z0 = s[0] + bf2f((unsigned short)(xpc.x & 0xFFFF));
        float z1 = s[1] + bf2f((unsigned short)(xpc.x >> 16));
        float z2 = s[2] + bf2f((unsigned short)(xpc.y & 0xFFFF));
        float z3 = s[3] + bf2f((unsigned short)(xpc.y >> 16));
        unsigned int v01 = (unsigned int)f2bf(fast_tanh(z0)) |
                           ((unsigned int)f2bf(fast_tanh(z1)) << 16);
        unsigned int v23 = (unsigned int)f2bf(fast_tanh(z2)) |
                           ((unsigned int)f2bf(fast_tanh(z3)) << 16);
        uint2 dvec = {v01, v23};
        unsigned short* p = hdst + pofs;
        asm volatile("global_store_dwordx2 %0, %1, off sc0 sc1"
                     :: "v"(p), "v"(dvec) : "memory");
      }
      // order h store before flag publish; publish ASAP (critical path)
      asm volatile("s_waitcnt vmcnt(0)" ::: "memory");
      if (tid == 0) {
        int tv = t + 1;
        asm volatile("global_store_dword %0, %1, off sc0 sc1"
                     :: "v"(myflag), "v"(tv) : "memory");
      }
    } else {
      // drain iteration: just make sure h[512] fragments have landed
      asm volatile("s_waitcnt vmcnt(0)" ::: "memory");
      __builtin_amdgcn_sched_barrier(0);
    }

    // ---- fused y-tile (latency shadow): y[t-1] = h[t] @ w2o^T + b ----
    if (t > 0) {
      f32x4 ay[4];
#pragma unroll
      for (int i = 0; i < 4; ++i) ay[i] = (f32x4){0.f, 0.f, 0.f, 0.f};
#pragma unroll
      for (int kk = 0; kk < 32; ++kk)
        ay[kk & 3] = __builtin_amdgcn_mfma_f32_16x16x32_bf16(
            wo[kk], __builtin_bit_cast(bf16x8, ha[kk]), ay[kk & 3], 0, 0, 0);
      f32x4 sy = (ay[0] + ay[1]) + (ay[2] + ay[3]);
      sy[0] += bias_o.x; sy[1] += bias_o.y; sy[2] += bias_o.z; sy[3] += bias_o.w;
      // y[t-1][b0+l15][j0+g*4 .. +3]: ONE dwordx4 fp32 store
      *(f32x4*)(y + (size_t)(t - 1) * 65536 + pofs) = sy;
    }
  }
}

// ---------- launch ----------
extern "C" void kernel_launch(void* const* d_in, const int* in_sizes, int n_in,
                              void* d_out, int out_size, void* d_ws, size_t ws_size,
                              hipStream_t stream) {
  const float* x     = (const float*)d_in[0];   // (512,64,1024)
  const float* h0    = (const float*)d_in[1];   // (64,1024)
  const float* w_i2h = (const float*)d_in[2];   // (1024,2048)
  const float* b_i2h = (const float*)d_in[3];   // (1024)
  const float* w_h2o = (const float*)d_in[4];   // (1024,1024)
  const float* b_h2o = (const float*)d_in[5];   // (1024)

  // workspace: xproj bf16 (67,108,864) | hx 4 slices (524,288) | flags (16,384)
  //            | wx 2MB | wh 2MB | w2o 2MB   (~73.9 MB)
  char* ws = (char*)d_ws;
  unsigned short* xproj = (unsigned short*)ws;
  unsigned short* hx    = (unsigned short*)(ws + 67108864);
  int*            flags = (int*)(ws + 67108864 + 524288);
  unsigned short* wx    = (unsigned short*)(ws + 67108864 + 524288 + 16384);
  unsigned short* wh    = wx + 1024 * 1024;
  unsigned short* w2o   = wh + 1024 * 1024;
  float* y = (float*)d_out;                      // (512,64,1024) fp32

  convert_kernel<<<3136, 256, 0, stream>>>(w_i2h, w_h2o, h0, wx, wh, w2o, hx, flags);

  // xproj = x @ wx^T + b_i2h   (M=32768, N=1024, K=1024) -> ws
  gemm_bt<true, true><<<2048, 256, 0, stream>>>((const void*)x, wx, b_i2h,
                                                (void*)xproj, 32768, 1024, 1024);

  // persistent 512-step recurrence with fused (shifted) output GEMM -> d_out
  rnn_scan<<<SCAN_BLOCKS, 64, 0, stream>>>(xproj, wh, w2o, b_h2o, y, hx, flags);
}

// Round 13
// 1472.797 us; speedup vs baseline: 13.0856x; 1.0439x over previous
//
#include <hip/hip_runtime.h>
#include <math.h>

// ---------- types / helpers ----------
typedef __attribute__((ext_vector_type(8))) short bf16x8;   // 8 bf16 = 4 VGPR
typedef __attribute__((ext_vector_type(4))) int   i32x4;
typedef __attribute__((ext_vector_type(4))) float f32x4;    // MFMA acc
typedef __attribute__((ext_vector_type(4))) unsigned short u16x4;

__device__ __forceinline__ unsigned short f2bf(float x) {   // round-to-nearest-even
  unsigned int u = __builtin_bit_cast(unsigned int, x);
  return (unsigned short)((u + 0x7fffu + ((u >> 16) & 1u)) >> 16);
}
__device__ __forceinline__ float bf2f(unsigned short h) {
  unsigned int u = ((unsigned int)h) << 16;
  return __builtin_bit_cast(float, u);
}
// tanh via hw exp2: tanh(z) = 1 - 2/(e^{2z}+1)
__device__ __forceinline__ float fast_tanh(float z) {
  float e;
  asm("v_exp_f32 %0, %1" : "=v"(e) : "v"(z * 2.8853900817779268f));
  return 1.0f - 2.0f * __builtin_amdgcn_rcpf(e + 1.0f);
}

// ---------- K0: convert weights + h0 to bf16; zero barrier flags ----------
__global__ void convert_kernel(const float* __restrict__ w_i2h,
                               const float* __restrict__ w_h2o,
                               const float* __restrict__ h0,
                               unsigned short* __restrict__ wx,
                               unsigned short* __restrict__ wh,
                               unsigned short* __restrict__ w2o,
                               unsigned short* __restrict__ hx,
                               int* __restrict__ flags) {
  int idx = blockIdx.x * 256 + threadIdx.x;
  if (idx < 4096) flags[idx] = 0;          // padded flags (256 x 64B lines)
  int e = idx * 4;
  const float* src;
  unsigned short* dst;
  if (e < 2097152) {                       // w_i2h
    int row = e >> 11, col = e & 2047;
    src = w_i2h + e;
    dst = (col < 1024) ? (wx + row * 1024 + col) : (wh + row * 1024 + (col - 1024));
  } else if (e < 3145728) {                // w_h2o
    int i = e - 2097152; src = w_h2o + i; dst = w2o + i;
  } else {                                 // h0 -> hx slice 0
    int i = e - 3145728; src = h0 + i; dst = hx + i;
  }
  float4 v = *(const float4*)src;
  u16x4 o = {f2bf(v.x), f2bf(v.y), f2bf(v.z), f2bf(v.w)};
  *(u16x4*)dst = o;
}

// ---------- GEMM: C[M,N] = A[M,K] * B[N,K]^T + bias[N] ----------
// 128x128 tile, BK=64, 4 waves (2x2 of 64x64), 16x16x32 bf16 MFMA.
template <bool AF32, bool OUTBF16>
__global__ __launch_bounds__(256) void gemm_bt(const void* __restrict__ Ap,
                                               const unsigned short* __restrict__ B,
                                               const float* __restrict__ bias,
                                               void* __restrict__ Cp,
                                               int M, int N, int K) {
  __shared__ __attribute__((aligned(16))) unsigned short lA[128 * 64];
  __shared__ __attribute__((aligned(16))) unsigned short lB[128 * 64];
  const int tid = threadIdx.x;
  const int bx = blockIdx.x & 7;       // N/128 == 8
  const int by = blockIdx.x >> 3;
  const int lane = tid & 63, w = tid >> 6;
  const int g = lane >> 4, l15 = lane & 15;
  const int wm = w >> 1, wn = w & 1;

  f32x4 acc[4][4];
#pragma unroll
  for (int i = 0; i < 4; ++i)
#pragma unroll
    for (int j = 0; j < 4; ++j) acc[i][j] = (f32x4){0.f, 0.f, 0.f, 0.f};

  const int nK = K >> 6;
  for (int kt = 0; kt < nK; ++kt) {
    const int k0 = kt << 6;
#pragma unroll
    for (int i = 0; i < 4; ++i) {
      int cl = i * 256 + tid;
      int row = cl >> 3, cc = cl & 7;
      bf16x8 av;
      if (AF32) {
        const float* ap = (const float*)Ap + (size_t)(by * 128 + row) * K + k0 + cc * 8;
        float4 f0 = *(const float4*)ap;
        float4 f1 = *(const float4*)(ap + 4);
        av = (bf16x8){(short)f2bf(f0.x), (short)f2bf(f0.y), (short)f2bf(f0.z), (short)f2bf(f0.w),
                      (short)f2bf(f1.x), (short)f2bf(f1.y), (short)f2bf(f1.z), (short)f2bf(f1.w)};
      } else {
        const unsigned short* ap = (const unsigned short*)Ap + (size_t)(by * 128 + row) * K + k0 + cc * 8;
        av = *(const bf16x8*)ap;
      }
      *(bf16x8*)&lA[(row * 8 + (cc ^ (row & 7))) * 8] = av;
      const unsigned short* bp = B + (size_t)(bx * 128 + row) * K + k0 + cc * 8;
      bf16x8 bv = *(const bf16x8*)bp;
      *(bf16x8*)&lB[(row * 8 + (cc ^ (row & 7))) * 8] = bv;
    }
    __syncthreads();
#pragma unroll
    for (int kk = 0; kk < 2; ++kk) {
      bf16x8 av[4], bv[4];
#pragma unroll
      for (int mt = 0; mt < 4; ++mt) {
        int r = wm * 64 + mt * 16 + l15;
        av[mt] = *(const bf16x8*)&lA[(r * 8 + ((kk * 4 + g) ^ (r & 7))) * 8];
      }
#pragma unroll
      for (int nt = 0; nt < 4; ++nt) {
        int r = wn * 64 + nt * 16 + l15;
        bv[nt] = *(const bf16x8*)&lB[(r * 8 + ((kk * 4 + g) ^ (r & 7))) * 8];
      }
#pragma unroll
      for (int mt = 0; mt < 4; ++mt)
#pragma unroll
        for (int nt = 0; nt < 4; ++nt)
          acc[mt][nt] = __builtin_amdgcn_mfma_f32_16x16x32_bf16(av[mt], bv[nt], acc[mt][nt], 0, 0, 0);
    }
    __syncthreads();
  }
#pragma unroll
  for (int mt = 0; mt < 4; ++mt) {
    int grow = by * 128 + wm * 64 + mt * 16 + g * 4;
#pragma unroll
    for (int nt = 0; nt < 4; ++nt) {
      int col = bx * 128 + wn * 64 + nt * 16 + l15;
      float bs = bias[col];
#pragma unroll
      for (int r = 0; r < 4; ++r) {
        size_t off = (size_t)(grow + r) * N + col;
        float v = acc[mt][nt][r] + bs;
        if (OUTBF16) ((unsigned short*)Cp)[off] = f2bf(v);
        else ((float*)Cp)[off] = v;
      }
    }
  }
}

// ---------- K2: persistent scan + fused y-GEMM, drain-shadowed publish ----------
// R12 structure (256 blocks x 1 wave; operand-swapped MFMA; padded flags;
// 4-slice hx ring; y[t-1] from ha=h[t]). Change vs R12: the y-tile MFMAs are
// moved BETWEEN the h-store and the vmcnt(0)+flag-publish — the store's L3
// ack (~0.6us) completes underneath the 32 register-only y-MFMAs, so the
// group-wide flag publish happens ~0.3us earlier each step.
#define SCAN_BLOCKS 256
__global__ __launch_bounds__(64, 1) void rnn_scan(const unsigned short* __restrict__ xproj,
                                                  const unsigned short* __restrict__ wh,
                                                  const unsigned short* __restrict__ w2o,
                                                  const float* __restrict__ b_h2o,
                                                  float* __restrict__ y,
                                                  unsigned short* __restrict__ hx,
                                                  int* __restrict__ flags) {
  const int tid = threadIdx.x;          // 0..63
  const int b = blockIdx.x;
  const int jt = b >> 2, bt = b & 3;
  const int g = tid >> 4, l15 = tid & 15;
  const int j0 = jt * 16, b0 = bt * 16;

  // resident fragments: wh / w2o rows j0..j0+15 (lane l15 = row, g = k-slice)
  bf16x8 wb[32], wo[32];
#pragma unroll
  for (int kk = 0; kk < 32; ++kk) {
    wb[kk] = *(const bf16x8*)(wh  + (size_t)(j0 + l15) * 1024 + kk * 32 + g * 8);
    wo[kk] = *(const bf16x8*)(w2o + (size_t)(j0 + l15) * 1024 + kk * 32 + g * 8);
  }
  // after swap each lane outputs j = j0+g*4 .. +3 -> float4 bias
  const float4 bias_o = *(const float4*)(b_h2o + j0 + g * 4);

  const int* fl = flags + (bt * 64 + tid) * 16;   // 64B-padded flag lines
  int* myflag = flags + (bt * 64 + jt) * 16;

  // per-lane element offset for h-store / xp / y (batch b0+l15, j j0+g*4)
  const int pofs = (b0 + l15) * 1024 + j0 + g * 4;

  for (int t = 0; t <= 512; ++t) {
    const unsigned short* hsrc = hx + (size_t)(t & 3) * 65536 + (size_t)b0 * 1024;

    // prefetch xp for the recurrence (skip on the drain iteration)
    uint2 xpc;
    if (t < 512)
      xpc = *(const uint2*)(xproj + (size_t)t * 65536 + pofs);

    // barrier: wait for all 64 producers of my bt group (one coherent load/lane)
    int v;
    do {
      asm volatile("global_load_dword %0, %1, off sc0 sc1\n\ts_waitcnt vmcnt(0)"
                   : "=v"(v) : "v"(fl) : "memory");
    } while (__any(v < t));

    // coherent h[t] loads: B-fragments (lane l15 = batch col, g = k-slice)
    i32x4 ha[32];
#pragma unroll
    for (int kk = 0; kk < 32; ++kk) {
      const unsigned short* p = hsrc + (size_t)l15 * 1024 + kk * 32 + g * 8;
      asm volatile("global_load_dwordx4 %0, %1, off sc0 sc1"
                   : "=v"(ha[kk]) : "v"(p) : "memory");
    }

    if (t < 512) {
      unsigned short* hdst = hx + (size_t)((t + 1) & 3) * 65536;
      f32x4 acc[4];
#pragma unroll
      for (int i = 0; i < 4; ++i) acc[i] = (f32x4){0.f, 0.f, 0.f, 0.f};

      // pipelined consume: counted vmcnt + sched_barrier (rule 18)
      // D[r=j][c=batch] = sum_k wh[j0+r][k] * h[b0+c][k]
#define MFMA_GROUP(base, n)                                                     \
      asm volatile("s_waitcnt vmcnt(" #n ")" ::: "memory");                     \
      __builtin_amdgcn_sched_barrier(0);                                        \
      _Pragma("unroll")                                                         \
      for (int kk = base; kk < base + 8; ++kk)                                  \
        acc[kk & 3] = __builtin_amdgcn_mfma_f32_16x16x32_bf16(                  \
            wb[kk], __builtin_bit_cast(bf16x8, ha[kk]), acc[kk & 3], 0, 0, 0);

      MFMA_GROUP(0, 24)
      MFMA_GROUP(8, 16)
      MFMA_GROUP(16, 8)
      MFMA_GROUP(24, 0)
#undef MFMA_GROUP

      f32x4 s = (acc[0] + acc[1]) + (acc[2] + acc[3]);

      // h_next[b0+l15][j0+g*4 .. +3] = tanh(s + xp): ONE dwordx2 store (no wait)
      {
        float z0 = s[0] + bf2f((unsigned short)(xpc.x & 0xFFFF));
        float z1 = s[1] + bf2f((unsigned short)(xpc.x >> 16));
        float z2 = s[2] + bf2f((unsigned short)(xpc.y & 0xFFFF));
        float z3 = s[3] + bf2f((unsigned short)(xpc.y >> 16));
        unsigned int v01 = (unsigned int)f2bf(fast_tanh(z0)) |
                           ((unsigned int)f2bf(fast_tanh(z1)) << 16);
        unsigned int v23 = (unsigned int)f2bf(fast_tanh(z2)) |
                           ((unsigned int)f2bf(fast_tanh(z3)) << 16);
        uint2 dvec = {v01, v23};
        unsigned short* p = hdst + pofs;
        asm volatile("global_store_dwordx2 %0, %1, off sc0 sc1"
                     :: "v"(p), "v"(dvec) : "memory");
      }

      // ---- y-MFMAs (register-only) run while the h-store ack drains ----
      f32x4 ay[4];
#pragma unroll
      for (int i = 0; i < 4; ++i) ay[i] = (f32x4){0.f, 0.f, 0.f, 0.f};
      if (t > 0) {
#pragma unroll
        for (int kk = 0; kk < 32; ++kk)
          ay[kk & 3] = __builtin_amdgcn_mfma_f32_16x16x32_bf16(
              wo[kk], __builtin_bit_cast(bf16x8, ha[kk]), ay[kk & 3], 0, 0, 0);
      }
      __builtin_amdgcn_sched_barrier(0);

      // h store ack has completed under the y-MFMAs: publish is ~free now
      asm volatile("s_waitcnt vmcnt(0)" ::: "memory");
      if (tid == 0) {
        int tv = t + 1;
        asm volatile("global_store_dword %0, %1, off sc0 sc1"
                     :: "v"(myflag), "v"(tv) : "memory");
      }

      // y epilogue (off the critical path)
      if (t > 0) {
        f32x4 sy = (ay[0] + ay[1]) + (ay[2] + ay[3]);
        sy[0] += bias_o.x; sy[1] += bias_o.y; sy[2] += bias_o.z; sy[3] += bias_o.w;
        *(f32x4*)(y + (size_t)(t - 1) * 65536 + pofs) = sy;
      }
    } else {
      // drain iteration: ensure h[512] fragments landed, then emit y[511]
      asm volatile("s_waitcnt vmcnt(0)" ::: "memory");
      __builtin_amdgcn_sched_barrier(0);
      f32x4 ay[4];
#pragma unroll
      for (int i = 0; i < 4; ++i) ay[i] = (f32x4){0.f, 0.f, 0.f, 0.f};
#pragma unroll
      for (int kk = 0; kk < 32; ++kk)
        ay[kk & 3] = __builtin_amdgcn_mfma_f32_16x16x32_bf16(
            wo[kk], __builtin_bit_cast(bf16x8, ha[kk]), ay[kk & 3], 0, 0, 0);
      f32x4 sy = (ay[0] + ay[1]) + (ay[2] + ay[3]);
      sy[0] += bias_o.x; sy[1] += bias_o.y; sy[2] += bias_o.z; sy[3] += bias_o.w;
      *(f32x4*)(y + (size_t)(t - 1) * 65536 + pofs) = sy;
    }
  }
}

// ---------- launch ----------
extern "C" void kernel_launch(void* const* d_in, const int* in_sizes, int n_in,
                              void* d_out, int out_size, void* d_ws, size_t ws_size,
                              hipStream_t stream) {
  const float* x     = (const float*)d_in[0];   // (512,64,1024)
  const float* h0    = (const float*)d_in[1];   // (64,1024)
  const float* w_i2h = (const float*)d_in[2];   // (1024,2048)
  const float* b_i2h = (const float*)d_in[3];   // (1024)
  const float* w_h2o = (const float*)d_in[4];   // (1024,1024)
  const float* b_h2o = (const float*)d_in[5];   // (1024)

  // workspace: xproj bf16 (67,108,864) | hx 4 slices (524,288) | flags (16,384)
  //            | wx 2MB | wh 2MB | w2o 2MB   (~73.9 MB)
  char* ws = (char*)d_ws;
  unsigned short* xproj = (unsigned short*)ws;
  unsigned short* hx    = (unsigned short*)(ws + 67108864);
  int*            flags = (int*)(ws + 67108864 + 524288);
  unsigned short* wx    = (unsigned short*)(ws + 67108864 + 524288 + 16384);
  unsigned short* wh    = wx + 1024 * 1024;
  unsigned short* w2o   = wh + 1024 * 1024;
  float* y = (float*)d_out;                      // (512,64,1024) fp32

  convert_kernel<<<3136, 256, 0, stream>>>(w_i2h, w_h2o, h0, wx, wh, w2o, hx, flags);

  // xproj = x @ wx^T + b_i2h   (M=32768, N=1024, K=1024) -> ws
  gemm_bt<true, true><<<2048, 256, 0, stream>>>((const void*)x, wx, b_i2h,
                                                (void*)xproj, 32768, 1024, 1024);

  // persistent 512-step recurrence with fused (shifted) output GEMM -> d_out
  rnn_scan<<<SCAN_BLOCKS, 64, 0, stream>>>(xproj, wh, w2o, b_h2o, y, hx, flags);
}